// Round 1
// baseline (247.924 us; speedup 1.0000x reference)
//
#include <hip/hip_runtime.h>

#define BATCH  4
#define NPTS   4096      // 64*64 top-surface points per batch
#define MPTS   8192      // cloud points per batch
#define TILE   256
#define MSPLIT 8         // dist1: M-loop split across blocks
#define NSPLIT 4         // dist2: N-loop split across blocks
#define HUGEF  3.0e38f

// vertices [B,3,64,32,64]; take y=31 (last), n = x*64 + z
__device__ __forceinline__ float vtop(const float* __restrict__ v, int b, int c, int n) {
    // idx = b*3*131072 + c*131072 + x*2048 + 31*64 + z
    return v[b * 393216 + c * 131072 + ((n >> 6) << 11) + 1984 + (n & 63)];
}

__device__ __forceinline__ void atomicMinF(float* addr, float val) {
    // valid for non-negative floats only (bit pattern order == float order)
    atomicMin((unsigned int*)addr, __float_as_uint(val));
}

// dist1[n] = min over VALID m of ||v_n - p_m||^2
__global__ void __launch_bounds__(256) dist1_kernel(const float* __restrict__ vert,
                                                    const float* __restrict__ pc,
                                                    float* __restrict__ dist1) {
    const int blk    = blockIdx.x;
    const int mchunk = blk % MSPLIT;
    const int ntile  = (blk / MSPLIT) % (NPTS / TILE);
    const int b      = blk / (MSPLIT * (NPTS / TILE));
    const int n      = ntile * TILE + threadIdx.x;

    const float vx = (vtop(vert, b, 0, n) - 0.5f) * 2.0f;
    const float vy = (vtop(vert, b, 1, n) - 0.5f) * 2.0f;
    const float vz = (vtop(vert, b, 2, n) - 0.5f) * 2.0f;

    __shared__ float px[TILE], py[TILE], pz[TILE];

    const int mlen = MPTS / MSPLIT;       // 1024
    const int m0   = mchunk * mlen;
    const float* pcb = pc + (size_t)b * 3 * MPTS;

    float best = HUGEF;
    for (int t = 0; t < mlen; t += TILE) {
        const int m = m0 + t + threadIdx.x;
        px[threadIdx.x] = pcb[m];
        py[threadIdx.x] = pcb[MPTS + m];
        pz[threadIdx.x] = pcb[2 * MPTS + m];
        __syncthreads();
#pragma unroll 8
        for (int j = 0; j < TILE; ++j) {
            const float qx = px[j], qy = py[j], qz = pz[j];
            const float dx = vx - qx, dy = vy - qy, dz = vz - qz;
            float d = dx * dx + dy * dy + dz * dz;
            const bool valid = !(qx == 0.0f && qy == 0.0f && qz == 0.0f);
            best = fminf(best, valid ? d : HUGEF);
        }
        __syncthreads();
    }
    atomicMinF(&dist1[b * NPTS + n], best);
}

// dist2[m] = min over ALL n of ||v_n - p_m||^2
__global__ void __launch_bounds__(256) dist2_kernel(const float* __restrict__ vert,
                                                    const float* __restrict__ pc,
                                                    float* __restrict__ dist2) {
    const int blk    = blockIdx.x;
    const int nchunk = blk % NSPLIT;
    const int mtile  = (blk / NSPLIT) % (MPTS / TILE);
    const int b      = blk / (NSPLIT * (MPTS / TILE));
    const int m      = mtile * TILE + threadIdx.x;

    const float* pcb = pc + (size_t)b * 3 * MPTS;
    const float qx = pcb[m];
    const float qy = pcb[MPTS + m];
    const float qz = pcb[2 * MPTS + m];

    __shared__ float sx[TILE], sy[TILE], sz[TILE];

    const int nlen = NPTS / NSPLIT;       // 1024
    const int n0   = nchunk * nlen;

    float best = HUGEF;
    for (int t = 0; t < nlen; t += TILE) {
        const int n = n0 + t + threadIdx.x;
        sx[threadIdx.x] = (vtop(vert, b, 0, n) - 0.5f) * 2.0f;
        sy[threadIdx.x] = (vtop(vert, b, 1, n) - 0.5f) * 2.0f;
        sz[threadIdx.x] = (vtop(vert, b, 2, n) - 0.5f) * 2.0f;
        __syncthreads();
#pragma unroll 8
        for (int j = 0; j < TILE; ++j) {
            const float dx = qx - sx[j], dy = qy - sy[j], dz = qz - sz[j];
            const float d = dx * dx + dy * dy + dz * dz;
            best = fminf(best, d);
        }
        __syncthreads();
    }
    atomicMinF(&dist2[b * MPTS + m], best);
}

// one block per batch: loss_b = mean(dist1) + sum(valid ? dist2 : 0)/max(nvalid,1)
__global__ void __launch_bounds__(256) reduce_kernel(const float* __restrict__ dist1,
                                                     const float* __restrict__ dist2,
                                                     const float* __restrict__ pc,
                                                     float* __restrict__ out) {
    const int b   = blockIdx.x;
    const int tid = threadIdx.x;

    float s1 = 0.0f;
    for (int n = tid; n < NPTS; n += 256) s1 += dist1[b * NPTS + n];

    const float* pcb = pc + (size_t)b * 3 * MPTS;
    float s2 = 0.0f;
    float cnt = 0.0f;
    for (int m = tid; m < MPTS; m += 256) {
        const float qx = pcb[m], qy = pcb[MPTS + m], qz = pcb[2 * MPTS + m];
        const bool valid = !(qx == 0.0f && qy == 0.0f && qz == 0.0f);
        if (valid) { s2 += dist2[b * MPTS + m]; cnt += 1.0f; }
    }

    __shared__ float r1[256], r2[256], rc[256];
    r1[tid] = s1; r2[tid] = s2; rc[tid] = cnt;
    __syncthreads();
    for (int s = 128; s > 0; s >>= 1) {
        if (tid < s) {
            r1[tid] += r1[tid + s];
            r2[tid] += r2[tid + s];
            rc[tid] += rc[tid + s];
        }
        __syncthreads();
    }
    if (tid == 0) {
        const float loss = r1[0] / (float)NPTS + r2[0] / fmaxf(rc[0], 1.0f);
        atomicAdd(out, loss * (1.0f / (float)BATCH));
    }
}

extern "C" void kernel_launch(void* const* d_in, const int* in_sizes, int n_in,
                              void* d_out, int out_size, void* d_ws, size_t ws_size,
                              hipStream_t stream) {
    const float* vert = (const float*)d_in[0];
    const float* pc   = (const float*)d_in[1];
    float* out   = (float*)d_out;
    float* dist1 = (float*)d_ws;                    // BATCH*NPTS floats
    float* dist2 = dist1 + BATCH * NPTS;            // BATCH*MPTS floats

    const size_t distBytes = (size_t)(BATCH * NPTS + BATCH * MPTS) * sizeof(float);
    // 0x7f7f7f7f == 3.3961514e38f — acts as +inf for the atomic min
    hipMemsetAsync(d_ws, 0x7f, distBytes, stream);
    hipMemsetAsync(d_out, 0, sizeof(float), stream);

    dist1_kernel<<<BATCH * (NPTS / TILE) * MSPLIT, 256, 0, stream>>>(vert, pc, dist1);
    dist2_kernel<<<BATCH * (MPTS / TILE) * NSPLIT, 256, 0, stream>>>(vert, pc, dist2);
    reduce_kernel<<<BATCH, 256, 0, stream>>>(dist1, dist2, pc, out);
}

// Round 2
// 99.494 us; speedup vs baseline: 2.4918x; 2.4918x over previous
//
#include <hip/hip_runtime.h>

#define BATCH   4
#define NPTS    4096      // 64*64 top-surface points per batch
#define MPTS    8192      // cloud points per batch
#define TPB     256
#define VPT     8         // points per thread (register tile)
#define MSPLIT  32        // dist1: chunks over M -> MLEN=256
#define NSPLIT  16        // dist2: chunks over N -> NLEN=256
#define MLEN    (MPTS / MSPLIT)           // 256
#define NLEN    (NPTS / NSPLIT)           // 256
#define D1_NBLK (NPTS / (TPB * VPT))      // 2
#define D2_MBLK (MPTS / (TPB * VPT))      // 4
#define D1_BLOCKS (BATCH * D1_NBLK * MSPLIT)  // 256
#define D2_BLOCKS (BATCH * D2_MBLK * NSPLIT)  // 256
#define BIGF    1.0e30f

// vertices [B,3,64,32,64]; take y=31 (last), n = x*64 + z
__device__ __forceinline__ float vtop(const float* __restrict__ v, int b, int c, int n) {
    return v[b * 393216 + c * 131072 + ((n >> 6) << 11) + 1984 + (n & 63)];
}

__device__ __forceinline__ void atomicMinF(float* addr, float val) {
    atomicMin((unsigned int*)addr, __float_as_uint(val));  // val must be >= 0
}

// Fused both-direction chamfer min kernel.
// use_atomic==0: plain stores of per-chunk partial mins into part1/part2.
// use_atomic==1: atomicMin into dist1f/dist2f (pre-initialized to +big).
__global__ void __launch_bounds__(TPB) dist_kernel(const float* __restrict__ vert,
                                                   const float* __restrict__ pc,
                                                   float* __restrict__ part1,
                                                   float* __restrict__ part2,
                                                   float* __restrict__ dist1f,
                                                   float* __restrict__ dist2f,
                                                   int use_atomic) {
    __shared__ float4 tile[TPB];
    const int tid = threadIdx.x;
    int blk = blockIdx.x;

    if (blk < D1_BLOCKS) {
        // ---- dist1: each thread owns 8 v-points; min over a 256-point q chunk ----
        const int c  = blk % MSPLIT;
        const int nb = (blk / MSPLIT) % D1_NBLK;
        const int b  = blk / (MSPLIT * D1_NBLK);
        const float* pcb = pc + (size_t)b * 3 * MPTS;

        {   // stage q chunk: (qx,qy,qz, 0.5*||q||^2 or BIG if padded)
            const int m = c * MLEN + tid;
            const float qx = pcb[m], qy = pcb[MPTS + m], qz = pcb[2 * MPTS + m];
            const bool valid = !(qx == 0.0f && qy == 0.0f && qz == 0.0f);
            const float qn2 = valid ? 0.5f * (qx * qx + qy * qy + qz * qz) : BIGF;
            tile[tid] = make_float4(qx, qy, qz, qn2);
        }

        float vx[VPT], vy[VPT], vz[VPT], best[VPT];
        const int nbase = nb * (TPB * VPT) + tid;
#pragma unroll
        for (int k = 0; k < VPT; ++k) {
            const int n = nbase + k * TPB;
            vx[k] = (vtop(vert, b, 0, n) - 0.5f) * 2.0f;
            vy[k] = (vtop(vert, b, 1, n) - 0.5f) * 2.0f;
            vz[k] = (vtop(vert, b, 2, n) - 0.5f) * 2.0f;
            best[k] = BIGF;
        }
        __syncthreads();

#pragma unroll 4
        for (int j = 0; j < MLEN; ++j) {
            const float4 q = tile[j];
#pragma unroll
            for (int k = 0; k < VPT; ++k) {
                // e = 0.5||q||^2 - v.q   (3 fma with neg modifiers + 1 min)
                best[k] = fminf(best[k],
                    fmaf(-vx[k], q.x, fmaf(-vy[k], q.y, fmaf(-vz[k], q.z, q.w))));
            }
        }

        if (use_atomic) {
#pragma unroll
            for (int k = 0; k < VPT; ++k) {
                const int n = nbase + k * TPB;
                const float vv = vx[k]*vx[k] + vy[k]*vy[k] + vz[k]*vz[k];
                atomicMinF(&dist1f[b * NPTS + n], fmaxf(vv + 2.0f * best[k], 0.0f));
            }
        } else {
            float* outp = part1 + (size_t)c * (BATCH * NPTS) + (size_t)b * NPTS;
#pragma unroll
            for (int k = 0; k < VPT; ++k) {
                const int n = nbase + k * TPB;
                const float vv = vx[k]*vx[k] + vy[k]*vy[k] + vz[k]*vz[k];
                outp[n] = fmaxf(vv + 2.0f * best[k], 0.0f);
            }
        }
    } else {
        // ---- dist2: each thread owns 8 p-points; min over a 256-point v chunk ----
        blk -= D1_BLOCKS;
        const int c  = blk % NSPLIT;
        const int mb = (blk / NSPLIT) % D2_MBLK;
        const int b  = blk / (NSPLIT * D2_MBLK);
        const float* pcb = pc + (size_t)b * 3 * MPTS;

        {   // stage v chunk: (vx,vy,vz, 0.5*||v||^2)
            const int n = c * NLEN + tid;
            const float sx = (vtop(vert, b, 0, n) - 0.5f) * 2.0f;
            const float sy = (vtop(vert, b, 1, n) - 0.5f) * 2.0f;
            const float sz = (vtop(vert, b, 2, n) - 0.5f) * 2.0f;
            tile[tid] = make_float4(sx, sy, sz, 0.5f * (sx*sx + sy*sy + sz*sz));
        }

        float qx[VPT], qy[VPT], qz[VPT], best[VPT];
        const int mbase = mb * (TPB * VPT) + tid;
#pragma unroll
        for (int k = 0; k < VPT; ++k) {
            const int m = mbase + k * TPB;
            qx[k] = pcb[m];
            qy[k] = pcb[MPTS + m];
            qz[k] = pcb[2 * MPTS + m];
            best[k] = BIGF;
        }
        __syncthreads();

#pragma unroll 4
        for (int j = 0; j < NLEN; ++j) {
            const float4 t = tile[j];
#pragma unroll
            for (int k = 0; k < VPT; ++k) {
                best[k] = fminf(best[k],
                    fmaf(-qx[k], t.x, fmaf(-qy[k], t.y, fmaf(-qz[k], t.z, t.w))));
            }
        }

        if (use_atomic) {
#pragma unroll
            for (int k = 0; k < VPT; ++k) {
                const int m = mbase + k * TPB;
                const float qq = qx[k]*qx[k] + qy[k]*qy[k] + qz[k]*qz[k];
                atomicMinF(&dist2f[b * MPTS + m], fmaxf(qq + 2.0f * best[k], 0.0f));
            }
        } else {
            float* outp = part2 + (size_t)c * (BATCH * MPTS) + (size_t)b * MPTS;
#pragma unroll
            for (int k = 0; k < VPT; ++k) {
                const int m = mbase + k * TPB;
                const float qq = qx[k]*qx[k] + qy[k]*qy[k] + qz[k]*qz[k];
                outp[m] = fmaxf(qq + 2.0f * best[k], 0.0f);
            }
        }
    }
}

// sums layout: sums[0..3]=sum(dist1)/batch, sums[4..7]=sum(valid dist2), sums[8..11]=nvalid
__global__ void __launch_bounds__(TPB) reduce_kernel(const float* __restrict__ part1,
                                                     const float* __restrict__ part2,
                                                     const float* __restrict__ dist1f,
                                                     const float* __restrict__ dist2f,
                                                     const float* __restrict__ pc,
                                                     float* __restrict__ sums,
                                                     int use_atomic) {
    const int gid = blockIdx.x * TPB + threadIdx.x;
    if (gid < BATCH * NPTS) {
        const int b = gid / NPTS;
        float s;
        if (use_atomic) {
            s = dist1f[gid];
        } else {
            float best = BIGF;
#pragma unroll
            for (int c = 0; c < MSPLIT; ++c)
                best = fminf(best, part1[(size_t)c * (BATCH * NPTS) + gid]);
            s = best;
        }
        for (int off = 32; off > 0; off >>= 1) s += __shfl_down(s, off, 64);
        if ((threadIdx.x & 63) == 0) atomicAdd(&sums[b], s);
    } else {
        const int g2 = gid - BATCH * NPTS;
        const int b  = g2 / MPTS;
        const int m  = g2 % MPTS;
        const float* pcb = pc + (size_t)b * 3 * MPTS;
        const float qx = pcb[m], qy = pcb[MPTS + m], qz = pcb[2 * MPTS + m];
        const bool valid = !(qx == 0.0f && qy == 0.0f && qz == 0.0f);
        float s = 0.0f, cn = 0.0f;
        if (valid) {
            if (use_atomic) {
                s = dist2f[g2];
            } else {
                float best = BIGF;
#pragma unroll
                for (int c = 0; c < NSPLIT; ++c)
                    best = fminf(best, part2[(size_t)c * (BATCH * MPTS) + g2]);
                s = best;
            }
            cn = 1.0f;
        }
        for (int off = 32; off > 0; off >>= 1) {
            s  += __shfl_down(s, off, 64);
            cn += __shfl_down(cn, off, 64);
        }
        if ((threadIdx.x & 63) == 0) {
            atomicAdd(&sums[4 + b], s);
            atomicAdd(&sums[8 + b], cn);
        }
    }
}

__global__ void finalize_kernel(const float* __restrict__ sums, float* __restrict__ out) {
    if (blockIdx.x == 0 && threadIdx.x == 0) {
        float t = 0.0f;
        for (int b = 0; b < BATCH; ++b)
            t += sums[b] * (1.0f / (float)NPTS) + sums[4 + b] / fmaxf(sums[8 + b], 1.0f);
        out[0] = t * (1.0f / (float)BATCH);
    }
}

extern "C" void kernel_launch(void* const* d_in, const int* in_sizes, int n_in,
                              void* d_out, int out_size, void* d_ws, size_t ws_size,
                              hipStream_t stream) {
    const float* vert = (const float*)d_in[0];
    const float* pc   = (const float*)d_in[1];
    float* out = (float*)d_out;

    const size_t part1_elems = (size_t)MSPLIT * BATCH * NPTS;   // 524288
    const size_t part2_elems = (size_t)NSPLIT * BATCH * MPTS;   // 524288
    const size_t need_partial = (part1_elems + part2_elems + 16) * sizeof(float); // ~4.2 MB

    const int grid_dist   = D1_BLOCKS + D2_BLOCKS;                       // 512
    const int grid_reduce = (BATCH * (NPTS + MPTS)) / TPB;               // 192

    if (ws_size >= need_partial) {
        float* part1 = (float*)d_ws;
        float* part2 = part1 + part1_elems;
        float* sums  = part2 + part2_elems;   // 12 floats used
        hipMemsetAsync(sums, 0, 16 * sizeof(float), stream);
        dist_kernel<<<grid_dist, TPB, 0, stream>>>(vert, pc, part1, part2, nullptr, nullptr, 0);
        reduce_kernel<<<grid_reduce, TPB, 0, stream>>>(part1, part2, nullptr, nullptr, pc, sums, 0);
        finalize_kernel<<<1, 64, 0, stream>>>(sums, out);
    } else {
        // fallback: atomicMin into per-point dist arrays (196 KB)
        float* dist1f = (float*)d_ws;                 // BATCH*NPTS
        float* dist2f = dist1f + BATCH * NPTS;        // BATCH*MPTS
        float* sums   = dist2f + BATCH * MPTS;        // 12 floats
        hipMemsetAsync(d_ws, 0x7f, (size_t)BATCH * (NPTS + MPTS) * sizeof(float), stream);
        hipMemsetAsync(sums, 0, 16 * sizeof(float), stream);
        dist_kernel<<<grid_dist, TPB, 0, stream>>>(vert, pc, nullptr, nullptr, dist1f, dist2f, 1);
        reduce_kernel<<<grid_reduce, TPB, 0, stream>>>(nullptr, nullptr, dist1f, dist2f, pc, sums, 1);
        finalize_kernel<<<1, 64, 0, stream>>>(sums, out);
    }
}

// Round 3
// 86.826 us; speedup vs baseline: 2.8554x; 1.1459x over previous
//
#include <hip/hip_runtime.h>

#define BATCH   4
#define NPTS    4096      // 64*64 top-surface points per batch
#define MPTS    8192      // cloud points per batch
#define TPB     256
#define VPT     8         // points per thread (register tile)
#define MSPLIT  32        // dist1: chunks over M -> MLEN=256
#define NSPLIT  16        // dist2: chunks over N -> NLEN=256
#define MLEN    (MPTS / MSPLIT)           // 256
#define NLEN    (NPTS / NSPLIT)           // 256
#define D1_NBLK (NPTS / (TPB * VPT))      // 2
#define D2_MBLK (MPTS / (TPB * VPT))      // 4
#define D1_BLOCKS (BATCH * D1_NBLK * MSPLIT)  // 256
#define D2_BLOCKS (BATCH * D2_MBLK * NSPLIT)  // 256
#define BIGF    1.0e30f

#define PART1_ELEMS (MSPLIT * BATCH * NPTS)   // 524288 floats (2 MB)
#define PART2_ELEMS (NSPLIT * BATCH * MPTS)   // 524288 floats (2 MB)

// reduce: 4 points per thread via float4
#define R1_BLOCKS ((BATCH * NPTS) / (TPB * 4))   // 16
#define R2_BLOCKS ((BATCH * MPTS) / (TPB * 4))   // 32
#define R_BLOCKS  (R1_BLOCKS + R2_BLOCKS)        // 48

// ctrl layout (floats): [0..3]=sum dist1 per batch, [4..7]=sum valid dist2,
// [8..11]=nvalid, [15]=ticket (as uint bits)
#define CTRL_FLOATS 16

// vertices [B,3,64,32,64]; take y=31 (last), n = x*64 + z
__device__ __forceinline__ float vtop(const float* __restrict__ v, int b, int c, int n) {
    return v[b * 393216 + c * 131072 + ((n >> 6) << 11) + 1984 + (n & 63)];
}

__global__ void __launch_bounds__(TPB) dist_kernel(const float* __restrict__ vert,
                                                   const float* __restrict__ pc,
                                                   float* __restrict__ part1,
                                                   float* __restrict__ part2,
                                                   float* __restrict__ ctrl) {
    __shared__ float4 tile[TPB];
    const int tid = threadIdx.x;
    int blk = blockIdx.x;

    if (blk == 0 && tid < CTRL_FLOATS) ctrl[tid] = 0.0f;   // zeroes sums + ticket

    if (blk < D1_BLOCKS) {
        // ---- dist1: each thread owns 8 v-points; min over a 256-point q chunk ----
        const int c  = blk % MSPLIT;
        const int nb = (blk / MSPLIT) % D1_NBLK;
        const int b  = blk / (MSPLIT * D1_NBLK);
        const float* pcb = pc + (size_t)b * 3 * MPTS;

        {   // stage q chunk: (qx,qy,qz, 0.5*||q||^2 or BIG if padded)
            const int m = c * MLEN + tid;
            const float qx = pcb[m], qy = pcb[MPTS + m], qz = pcb[2 * MPTS + m];
            const bool valid = !(qx == 0.0f && qy == 0.0f && qz == 0.0f);
            const float qn2 = valid ? 0.5f * (qx * qx + qy * qy + qz * qz) : BIGF;
            tile[tid] = make_float4(qx, qy, qz, qn2);
        }

        float vx[VPT], vy[VPT], vz[VPT], best[VPT];
        const int nbase = nb * (TPB * VPT) + tid;
#pragma unroll
        for (int k = 0; k < VPT; ++k) {
            const int n = nbase + k * TPB;
            vx[k] = (vtop(vert, b, 0, n) - 0.5f) * 2.0f;
            vy[k] = (vtop(vert, b, 1, n) - 0.5f) * 2.0f;
            vz[k] = (vtop(vert, b, 2, n) - 0.5f) * 2.0f;
            best[k] = BIGF;
        }
        __syncthreads();

#pragma unroll 4
        for (int j = 0; j < MLEN; ++j) {
            const float4 q = tile[j];
#pragma unroll
            for (int k = 0; k < VPT; ++k) {
                // e = 0.5||q||^2 - v.q   (3 fma with neg modifiers + 1 min)
                best[k] = fminf(best[k],
                    fmaf(-vx[k], q.x, fmaf(-vy[k], q.y, fmaf(-vz[k], q.z, q.w))));
            }
        }

        float* outp = part1 + (size_t)c * (BATCH * NPTS) + (size_t)b * NPTS;
#pragma unroll
        for (int k = 0; k < VPT; ++k) {
            const int n = nbase + k * TPB;
            const float vv = vx[k]*vx[k] + vy[k]*vy[k] + vz[k]*vz[k];
            outp[n] = fmaxf(vv + 2.0f * best[k], 0.0f);
        }
    } else {
        // ---- dist2: each thread owns 8 p-points; min over a 256-point v chunk ----
        blk -= D1_BLOCKS;
        const int c  = blk % NSPLIT;
        const int mb = (blk / NSPLIT) % D2_MBLK;
        const int b  = blk / (NSPLIT * D2_MBLK);
        const float* pcb = pc + (size_t)b * 3 * MPTS;

        {   // stage v chunk: (vx,vy,vz, 0.5*||v||^2)
            const int n = c * NLEN + tid;
            const float sx = (vtop(vert, b, 0, n) - 0.5f) * 2.0f;
            const float sy = (vtop(vert, b, 1, n) - 0.5f) * 2.0f;
            const float sz = (vtop(vert, b, 2, n) - 0.5f) * 2.0f;
            tile[tid] = make_float4(sx, sy, sz, 0.5f * (sx*sx + sy*sy + sz*sz));
        }

        float qx[VPT], qy[VPT], qz[VPT], best[VPT];
        const int mbase = mb * (TPB * VPT) + tid;
#pragma unroll
        for (int k = 0; k < VPT; ++k) {
            const int m = mbase + k * TPB;
            qx[k] = pcb[m];
            qy[k] = pcb[MPTS + m];
            qz[k] = pcb[2 * MPTS + m];
            best[k] = BIGF;
        }
        __syncthreads();

#pragma unroll 4
        for (int j = 0; j < NLEN; ++j) {
            const float4 t = tile[j];
#pragma unroll
            for (int k = 0; k < VPT; ++k) {
                best[k] = fminf(best[k],
                    fmaf(-qx[k], t.x, fmaf(-qy[k], t.y, fmaf(-qz[k], t.z, t.w))));
            }
        }

        float* outp = part2 + (size_t)c * (BATCH * MPTS) + (size_t)b * MPTS;
#pragma unroll
        for (int k = 0; k < VPT; ++k) {
            const int m = mbase + k * TPB;
            const float qq = qx[k]*qx[k] + qy[k]*qy[k] + qz[k]*qz[k];
            outp[m] = fmaxf(qq + 2.0f * best[k], 0.0f);
        }
    }
}

// 48 blocks: 0..15 reduce dist1 (4 pts/thread), 16..47 reduce dist2.
// Last block (ticket) finalizes out[0].
__global__ void __launch_bounds__(TPB) reduce_kernel(const float* __restrict__ part1,
                                                     const float* __restrict__ part2,
                                                     const float* __restrict__ pc,
                                                     float* __restrict__ ctrl,
                                                     float* __restrict__ out) {
    const int tid = threadIdx.x;
    const int wid = tid >> 6;
    __shared__ float rs[4], rc[4];

    float s = 0.0f, cn = 0.0f;
    int b;

    if (blockIdx.x < R1_BLOCKS) {
        const int gid = blockIdx.x * (TPB * 4) + tid * 4;   // [0, BATCH*NPTS)
        b = gid / NPTS;
        float4 best = make_float4(BIGF, BIGF, BIGF, BIGF);
#pragma unroll
        for (int c = 0; c < MSPLIT; ++c) {
            const float4 v = *(const float4*)&part1[(size_t)c * (BATCH * NPTS) + gid];
            best.x = fminf(best.x, v.x); best.y = fminf(best.y, v.y);
            best.z = fminf(best.z, v.z); best.w = fminf(best.w, v.w);
        }
        s = best.x + best.y + best.z + best.w;
    } else {
        const int g2 = (blockIdx.x - R1_BLOCKS) * (TPB * 4) + tid * 4;  // [0, BATCH*MPTS)
        b = g2 / MPTS;
        const int m = g2 % MPTS;
        float4 best = make_float4(BIGF, BIGF, BIGF, BIGF);
#pragma unroll
        for (int c = 0; c < NSPLIT; ++c) {
            const float4 v = *(const float4*)&part2[(size_t)c * (BATCH * MPTS) + g2];
            best.x = fminf(best.x, v.x); best.y = fminf(best.y, v.y);
            best.z = fminf(best.z, v.z); best.w = fminf(best.w, v.w);
        }
        const float* pcb = pc + (size_t)b * 3 * MPTS;
        const float4 qx = *(const float4*)&pcb[m];
        const float4 qy = *(const float4*)&pcb[MPTS + m];
        const float4 qz = *(const float4*)&pcb[2 * MPTS + m];
        const bool v0 = !(qx.x == 0.0f && qy.x == 0.0f && qz.x == 0.0f);
        const bool v1 = !(qx.y == 0.0f && qy.y == 0.0f && qz.y == 0.0f);
        const bool v2 = !(qx.z == 0.0f && qy.z == 0.0f && qz.z == 0.0f);
        const bool v3 = !(qx.w == 0.0f && qy.w == 0.0f && qz.w == 0.0f);
        s  = (v0 ? best.x : 0.0f) + (v1 ? best.y : 0.0f)
           + (v2 ? best.z : 0.0f) + (v3 ? best.w : 0.0f);
        cn = (float)v0 + (float)v1 + (float)v2 + (float)v3;
    }

    // wave reduce (width 64), then cross-wave via LDS
    for (int off = 32; off > 0; off >>= 1) {
        s  += __shfl_down(s, off, 64);
        cn += __shfl_down(cn, off, 64);
    }
    if ((tid & 63) == 0) { rs[wid] = s; rc[wid] = cn; }
    __syncthreads();

    if (tid == 0) {
        const float ts = rs[0] + rs[1] + rs[2] + rs[3];
        if (blockIdx.x < R1_BLOCKS) {
            atomicAdd(&ctrl[b], ts);
        } else {
            atomicAdd(&ctrl[4 + b], ts);
            atomicAdd(&ctrl[8 + b], rc[0] + rc[1] + rc[2] + rc[3]);
        }
        __threadfence();
        const unsigned int old = atomicAdd((unsigned int*)&ctrl[15], 1u);
        if (old == R_BLOCKS - 1) {
            // last block: all sums are globally visible; read via atomic RMW
            float t = 0.0f;
            for (int bb = 0; bb < BATCH; ++bb) {
                const float s1 = atomicAdd(&ctrl[bb], 0.0f);
                const float s2 = atomicAdd(&ctrl[4 + bb], 0.0f);
                const float nv = atomicAdd(&ctrl[8 + bb], 0.0f);
                t += s1 * (1.0f / (float)NPTS) + s2 / fmaxf(nv, 1.0f);
            }
            out[0] = t * (1.0f / (float)BATCH);
        }
    }
}

extern "C" void kernel_launch(void* const* d_in, const int* in_sizes, int n_in,
                              void* d_out, int out_size, void* d_ws, size_t ws_size,
                              hipStream_t stream) {
    const float* vert = (const float*)d_in[0];
    const float* pc   = (const float*)d_in[1];
    float* out = (float*)d_out;

    float* part1 = (float*)d_ws;
    float* part2 = part1 + PART1_ELEMS;
    float* ctrl  = part2 + PART2_ELEMS;   // 16 floats

    dist_kernel<<<D1_BLOCKS + D2_BLOCKS, TPB, 0, stream>>>(vert, pc, part1, part2, ctrl);
    reduce_kernel<<<R_BLOCKS, TPB, 0, stream>>>(part1, part2, pc, ctrl, out);
}